// Round 18
// baseline (46.396 us; speedup 1.0000x reference)
//
#include <hip/hip_runtime.h>

// Conv4d via implicit GEMM on MFMA (bf16 in, fp32 accum).
// x (2,16,20^4) f32, w (16,32,3^4) f32 -> out (2,32,18^4) f32
//
// R18: interpolate the two levers that measurably moved conv:
//   occupancy (R16: 1-tile, 4 w/SIMD, 40.8 total) and
//   reads/MFMA (R17: 3-tile, 2 w/SIMD, 44.9 total).
// 2 tiles/wave: acc[3][2] = 96 AGPR -> fits 3 waves/SIMD at
// launch_bounds(384,3) (cap 170 = 96 AGPR + ~65 VGPR). Block = 384 thr
// (6 waves x 2 stride-30 tiles = 12 tiles = exact site cover). Per ab:
// 9 af ds_reads + 6 bv global + 18 MFMA (0.83 reads/MFMA) at 12 waves/CU.
// Pipe floors/CU: LDS 6.2us || L1 5.5us.
// Keeps: d-shift, af-LDS dbuf ([tap][ic8][oc][ic_lo], wave-uniform gload16),
// bv direct-global from xt, stride-30 in-wave shfl epilogue, XCD swizzle,
// xt/wt prepass (all verified R11-R17).

typedef unsigned short ushort_t;
typedef __attribute__((ext_vector_type(8)))  __bf16 bf16x8;
typedef __attribute__((ext_vector_type(16))) float  f32x16;
typedef __attribute__((ext_vector_type(4)))  unsigned int uint4v;

__device__ __forceinline__ ushort_t f2bf(float f) {
    union { float f; unsigned int u; } v; v.f = f;
    unsigned int r = v.u + 0x7FFFu + ((v.u >> 16) & 1u);   // RNE
    return (ushort_t)(r >> 16);
}

__device__ __forceinline__ void gload16(const ushort_t* g, ushort_t* l) {
    __builtin_amdgcn_global_load_lds(
        (const __attribute__((address_space(1))) unsigned int*)g,
        (__attribute__((address_space(3))) unsigned int*)l, 16, 0, 0);
}

// ---------- fused prepass (verified R5-R17) ----------
// blocks 0..1249: x (NCHW f32) -> xt (N,spatial,ic bf16)
// blocks 1250..1411: w -> wt [tap][ic8][oc][ic_lo] bf16
__global__ __launch_bounds__(256) void prepass(const float* __restrict__ x,
                                               const float* __restrict__ w,
                                               ushort_t* __restrict__ xt,
                                               ushort_t* __restrict__ wt) {
    const int blk = blockIdx.x;
    if (blk < 1250) {
        const int g = blk * 256 + threadIdx.x;          // 0..319999
        const int n = g / 160000, rem = g % 160000;
        const float* xs = x + (size_t)n * 2560000 + rem;
        unsigned int pk[8];
        #pragma unroll
        for (int e = 0; e < 8; ++e) {
            unsigned int lo = f2bf(xs[(size_t)(2 * e) * 160000]);
            unsigned int hi = f2bf(xs[(size_t)(2 * e + 1) * 160000]);
            pk[e] = lo | (hi << 16);
        }
        uint4v* q = (uint4v*)xt + (size_t)g * 2;
        uint4v q0; q0[0] = pk[0]; q0[1] = pk[1]; q0[2] = pk[2]; q0[3] = pk[3];
        uint4v q1; q1[0] = pk[4]; q1[1] = pk[5]; q1[2] = pk[6]; q1[3] = pk[7];
        q[0] = q0; q[1] = q1;
    } else {
        const int s = (blk - 1250) * 256 + threadIdx.x;
        if (s < 41472) {
            const int ic = s / 2592, rem = s % 2592;
            const int oc = rem / 81, tap = rem % 81;
            wt[tap * 512 + (ic >> 3) * 256 + oc * 8 + (ic & 7)] = f2bf(w[s]);
        }
    }
}

// ---------- main conv: 6 waves x 2 tiles, af via LDS, bv direct-global ----------
__global__ __launch_bounds__(384, 3) void conv4d_mfma(
    const ushort_t* __restrict__ xt, const ushort_t* __restrict__ wt,
    float* __restrict__ out)
{
    __shared__ ushort_t lwt[2][4608];   // double-buffered wt tap-block, 9.2KB each

    // bijective XCD swizzle: 648 blocks = 8 XCDs x 81 contiguous tiles
    const int wgid = blockIdx.x;
    const int tile_ = (wgid & 7) * 81 + (wgid >> 3);
    const int n = tile_ / 324;
    const int rem_ = tile_ - n * 324;
    const int j = rem_ / 18, i = rem_ % 18;

    const int t = threadIdx.x;
    const int lane = t & 63, wv = t >> 6;   // wv 0..5
    const int col = lane & 31, ic8 = lane >> 5;

    // stride-30 tiles: wave wv owns T = 2wv+m (m=0,1); covers slab pos
    // 30T..30T+31, emits cols 0..29 -> epilogue fully in-wave (R15-R17).
    int sp[2]; int cb[2];
    #pragma unroll
    for (int m = 0; m < 2; ++m) {
        sp[m] = (2 * wv + m) * 30 + col;
        const int spc = sp[m] > 359 ? 359 : sp[m];   // clamped lanes feed only s>357
        cb[m] = spc * 32 + ic8 * 16;                 // BYTES into a slab
    }
    const int aoffB = ic8 * 512 + col * 16;          // BYTES into a 1024B tap block

    f32x16 acc[3][2];   // [d][m] — 96 AGPR
    #pragma unroll
    for (int d = 0; d < 3; ++d)
        #pragma unroll
        for (int m = 0; m < 2; ++m)
            #pragma unroll
            for (int r = 0; r < 16; ++r) acc[d][m][r] = 0.0f;

    const char* xnij = (const char*)(xt + (size_t)n * 2560000
                                        + (size_t)i * 128000 + (size_t)j * 6400);

    // prologue: stage wt tap-block 0 (wave-uniform dest; 576 chunks / 6 waves)
    {
        const ushort_t* gw = wt;
        gload16(gw + t * 8, lwt[0] + (wv << 9));                 // chunks 0..383
        if (t < 192) gload16(gw + 3072 + t * 8, lwt[0] + 3072 + (wv << 9)); // 384..575
    }

    for (int ab = 0; ab < 9; ++ab) {
        __syncthreads();   // lwt[ab&1] staged (barrier drains vmcnt)

        if (ab < 8) {      // prefetch next tap-block, lands by next barrier
            const ushort_t* gw = wt + (size_t)(ab + 1) * 4608;
            ushort_t* lw = lwt[(ab + 1) & 1];
            gload16(gw + t * 8, lw + (wv << 9));
            if (t < 192) gload16(gw + 3072 + t * 8, lw + 3072 + (wv << 9));
        }

        const int a = ab / 3, b = ab % 3;
        const char* xs = xnij + ((size_t)a * 128000 + (size_t)b * 6400) * 2;
        const char* wbase = (const char*)lwt[ab & 1];
        #pragma unroll
        for (int c = 0; c < 3; ++c) {
            bf16x8 af0 = *(const bf16x8*)(wbase + (c * 3 + 0) * 1024 + aoffB);
            bf16x8 af1 = *(const bf16x8*)(wbase + (c * 3 + 1) * 1024 + aoffB);
            bf16x8 af2 = *(const bf16x8*)(wbase + (c * 3 + 2) * 1024 + aoffB);
            #pragma unroll
            for (int m = 0; m < 2; ++m) {
                bf16x8 bv = *(const bf16x8*)(xs + cb[m] + c * 640);
                acc[0][m] = __builtin_amdgcn_mfma_f32_32x32x16_bf16(af0, bv, acc[0][m], 0, 0, 0);
                acc[1][m] = __builtin_amdgcn_mfma_f32_32x32x16_bf16(af1, bv, acc[1][m], 0, 0, 0);
                acc[2][m] = __builtin_amdgcn_mfma_f32_32x32x16_bf16(af2, bv, acc[2][m], 0, 0, 0);
            }
        }
    }

    // ---- epilogue: out(s) = acc0[col] + acc1[col+1] + acc2[col+2], in-wave ----
    float* outb = out + (size_t)n * 3359232 + (size_t)i * 5832 + (size_t)j * 324
                      + (size_t)ic8 * 419904;
    const int src1 = (lane & 32) | ((col + 1) & 31);
    const int src2 = (lane & 32) | ((col + 2) & 31);

    #pragma unroll
    for (int m = 0; m < 2; ++m) {
        const int s = sp[m];
        const int k = s / 20, ls = s % 20;
        const bool val = (col <= 29) && (ls <= 17) && (s <= 357);
        float* po = outb + k * 18 + ls;
        #pragma unroll
        for (int r = 0; r < 16; ++r) {
            const float v1 = __shfl(acc[1][m][r], src1, 64);
            const float v2 = __shfl(acc[2][m][r], src2, 64);
            const float res = acc[0][m][r] + v1 + v2;
            const int offr = ((r & 3) + 8 * (r >> 2)) * 104976;
            if (val) po[offr] = res;
        }
    }
}

extern "C" void kernel_launch(void* const* d_in, const int* in_sizes, int n_in,
                              void* d_out, int out_size, void* d_ws, size_t ws_size,
                              hipStream_t stream) {
    const float* x = (const float*)d_in[0];
    const float* w = (const float*)d_in[1];
    float* out = (float*)d_out;

    ushort_t* xt = (ushort_t*)d_ws;                              // 10.24 MB
    ushort_t* wt = (ushort_t*)((char*)d_ws + (size_t)10240000);  // 83 KB

    prepass<<<dim3(1412), 256, 0, stream>>>(x, w, xt, wt);
    conv4d_mfma<<<dim3(648), 384, 0, stream>>>(xt, wt, out);
}

// Round 19
// 40.641 us; speedup vs baseline: 1.1416x; 1.1416x over previous
//
#include <hip/hip_runtime.h>

// Conv4d via implicit GEMM on MFMA (bf16 in, fp32 accum).
// x (2,16,20^4) f32, w (16,32,3^4) f32 -> out (2,32,18^4) f32
//
// R19 = R16 (1 tile/wave, stride-30, af-via-LDS dbuf, bv direct-global,
// in-wave shfl epilogue, XCD swizzle) + two latency fixes:
//  (1) explicit 1-step-ahead REGISTER prefetch of bv: fully-unrolled ab
//      loop, parity-indexed (compile-time) bv sets -> each global load has
//      a full step (~300+ cyc) of compute cover instead of ~200 cyc.
//  (2) true 4 waves/SIMD: acc 48 AGPR + ~75 VGPR <= 128 under
//      launch_bounds(256,4); 4 blocks/CU (LDS 18.4KB), 16 waves/CU.
// Rationale: R18's ledger shows MFMA busy-time == its floor (7.5us) and
// ~32us idle; R13 (no barriers) killed the sync theories; the only
// mechanism consistent with R13/R16/R18 is per-step exposed VMEM latency
// with insufficient TLP.

typedef unsigned short ushort_t;
typedef __attribute__((ext_vector_type(8)))  __bf16 bf16x8;
typedef __attribute__((ext_vector_type(16))) float  f32x16;
typedef __attribute__((ext_vector_type(4)))  unsigned int uint4v;

__device__ __forceinline__ ushort_t f2bf(float f) {
    union { float f; unsigned int u; } v; v.f = f;
    unsigned int r = v.u + 0x7FFFu + ((v.u >> 16) & 1u);   // RNE
    return (ushort_t)(r >> 16);
}

__device__ __forceinline__ void gload16(const ushort_t* g, ushort_t* l) {
    __builtin_amdgcn_global_load_lds(
        (const __attribute__((address_space(1))) unsigned int*)g,
        (__attribute__((address_space(3))) unsigned int*)l, 16, 0, 0);
}

// ---------- fused prepass (verified R5-R18) ----------
// blocks 0..1249: x (NCHW f32) -> xt (N,spatial,ic bf16)
// blocks 1250..1411: w -> wt [tap][ic8][oc][ic_lo] bf16
__global__ __launch_bounds__(256) void prepass(const float* __restrict__ x,
                                               const float* __restrict__ w,
                                               ushort_t* __restrict__ xt,
                                               ushort_t* __restrict__ wt) {
    const int blk = blockIdx.x;
    if (blk < 1250) {
        const int g = blk * 256 + threadIdx.x;          // 0..319999
        const int n = g / 160000, rem = g % 160000;
        const float* xs = x + (size_t)n * 2560000 + rem;
        unsigned int pk[8];
        #pragma unroll
        for (int e = 0; e < 8; ++e) {
            unsigned int lo = f2bf(xs[(size_t)(2 * e) * 160000]);
            unsigned int hi = f2bf(xs[(size_t)(2 * e + 1) * 160000]);
            pk[e] = lo | (hi << 16);
        }
        uint4v* q = (uint4v*)xt + (size_t)g * 2;
        uint4v q0; q0[0] = pk[0]; q0[1] = pk[1]; q0[2] = pk[2]; q0[3] = pk[3];
        uint4v q1; q1[0] = pk[4]; q1[1] = pk[5]; q1[2] = pk[6]; q1[3] = pk[7];
        q[0] = q0; q[1] = q1;
    } else {
        const int s = (blk - 1250) * 256 + threadIdx.x;
        if (s < 41472) {
            const int ic = s / 2592, rem = s % 2592;
            const int oc = rem / 81, tap = rem % 81;
            wt[tap * 512 + (ic >> 3) * 256 + oc * 8 + (ic & 7)] = f2bf(w[s]);
        }
    }
}

// ---------- main conv: 1 tile/wave, af via LDS, bv reg-prefetched ----------
__global__ __launch_bounds__(256, 4) void conv4d_mfma(
    const ushort_t* __restrict__ xt, const ushort_t* __restrict__ wt,
    float* __restrict__ out)
{
    __shared__ ushort_t lwt[2][4608];   // double-buffered wt tap-block, 9.2KB each

    // bijective XCD swizzle: 1944 blocks = 8 XCDs x 243 contiguous
    const int wgid = blockIdx.x;
    const int g = (wgid & 7) * 243 + (wgid >> 3);
    const int n = g / 972;
    int rem = g - n * 972;
    const int j = rem / 54;  rem -= j * 54;
    const int i = rem / 3;
    const int q = rem - i * 3;                 // tile-quad 0..2

    const int t = threadIdx.x;
    const int lane = t & 63, wv = t >> 6;
    const int col = lane & 31, ic8 = lane >> 5;

    const int T = q * 4 + wv;                  // wave tile 0..11
    const int sp = T * 30 + col;               // slab position (stride-30 tiles)
    const int spc = sp > 359 ? 359 : sp;       // clamp: clamped lanes feed only s>357
    const int cb = spc * 32 + ic8 * 16;        // BYTES into a slab
    const int aoffB = ic8 * 512 + col * 16;    // BYTES into a 1024B tap block

    f32x16 acc0, acc1, acc2;                   // 48 AGPR
    #pragma unroll
    for (int r = 0; r < 16; ++r) { acc0[r] = 0.0f; acc1[r] = 0.0f; acc2[r] = 0.0f; }

    const char* xnij = (const char*)(xt + (size_t)n * 2560000
                                        + (size_t)i * 128000 + (size_t)j * 6400);

    // prologue: stage wt tap-block 0 (wave-uniform dest, R11/R16 pattern)
    {
        const ushort_t* gw = wt;
        gload16(gw + t * 8,        lwt[0] + (wv << 9));
        gload16(gw + 2048 + t * 8, lwt[0] + 2048 + (wv << 9));
        if (t < 64) gload16(gw + 4096 + t * 8, lwt[0] + 4096);
    }

    // preload bv set for ab=0 (parity 0)
    bf16x8 bvp[2][3];   // [parity][c] — all indices compile-time (full unroll)
    #pragma unroll
    for (int c = 0; c < 3; ++c)
        bvp[0][c] = *(const bf16x8*)(xnij + cb + c * 640);

    #pragma unroll
    for (int ab = 0; ab < 9; ++ab) {
        __syncthreads();   // lwt[ab&1] staged (barrier drains vmcnt)

        if (ab < 8) {
            // prefetch next wt tap-block (LDS-direct)
            const ushort_t* gw = wt + (size_t)(ab + 1) * 4608;
            ushort_t* lw = lwt[(ab + 1) & 1];
            gload16(gw + t * 8,        lw + (wv << 9));
            gload16(gw + 2048 + t * 8, lw + 2048 + (wv << 9));
            if (t < 64) gload16(gw + 4096 + t * 8, lw + 4096);

            // prefetch next step's 3 bv into registers (full step of cover)
            const int an = (ab + 1) / 3, bn = (ab + 1) % 3;
            const char* xsn = xnij + ((size_t)an * 128000 + (size_t)bn * 6400) * 2;
            #pragma unroll
            for (int c = 0; c < 3; ++c)
                bvp[(ab + 1) & 1][c] = *(const bf16x8*)(xsn + cb + c * 640);
        }

        const char* wbase = (const char*)lwt[ab & 1];
        #pragma unroll
        for (int c = 0; c < 3; ++c) {
            bf16x8 af0 = *(const bf16x8*)(wbase + (c * 3 + 0) * 1024 + aoffB);
            bf16x8 af1 = *(const bf16x8*)(wbase + (c * 3 + 1) * 1024 + aoffB);
            bf16x8 af2 = *(const bf16x8*)(wbase + (c * 3 + 2) * 1024 + aoffB);
            bf16x8 bv  = bvp[ab & 1][c];
            acc0 = __builtin_amdgcn_mfma_f32_32x32x16_bf16(af0, bv, acc0, 0, 0, 0);
            acc1 = __builtin_amdgcn_mfma_f32_32x32x16_bf16(af1, bv, acc1, 0, 0, 0);
            acc2 = __builtin_amdgcn_mfma_f32_32x32x16_bf16(af2, bv, acc2, 0, 0, 0);
        }
    }

    // ---- epilogue: out(s) = acc0[col] + acc1[col+1] + acc2[col+2], in-wave ----
    const int s = sp;
    const int k = s / 20, ls = s % 20;
    const bool val = (col <= 29) && (ls <= 17) && (s <= 357);
    float* po = out + (size_t)n * 3359232 + (size_t)i * 5832 + (size_t)j * 324
                    + (size_t)ic8 * 419904 + k * 18 + ls;
    const int src1 = (lane & 32) | ((col + 1) & 31);
    const int src2 = (lane & 32) | ((col + 2) & 31);

    #pragma unroll
    for (int r = 0; r < 16; ++r) {
        const float v1 = __shfl(acc1[r], src1, 64);
        const float v2 = __shfl(acc2[r], src2, 64);
        const float res = acc0[r] + v1 + v2;
        const int offr = ((r & 3) + 8 * (r >> 2)) * 104976;
        if (val) po[offr] = res;
    }
}

extern "C" void kernel_launch(void* const* d_in, const int* in_sizes, int n_in,
                              void* d_out, int out_size, void* d_ws, size_t ws_size,
                              hipStream_t stream) {
    const float* x = (const float*)d_in[0];
    const float* w = (const float*)d_in[1];
    float* out = (float*)d_out;

    ushort_t* xt = (ushort_t*)d_ws;                              // 10.24 MB
    ushort_t* wt = (ushort_t*)((char*)d_ws + (size_t)10240000);  // 83 KB

    prepass<<<dim3(1412), 256, 0, stream>>>(x, w, xt, wt);
    conv4d_mfma<<<dim3(1944), 256, 0, stream>>>(xt, wt, out);
}